// Round 4
// baseline (83.289 us; speedup 1.0000x reference)
//
#include <hip/hip_runtime.h>

#define BATCH 512
#define EMBED 512
#define BLOCK 256
#define TS 32        // gram tile size
#define KSPLIT 2     // split-K slabs

// d_ws layout (floats):
//   [0 .. 2*B*B)        : Dp partial gram slabs (2 MB)
//   [2*B*B .. 2*B*B+512): per-anchor partials
//   [2*B*B+512]         : ticket counter (as int)

// ---------------- Kernel 1: partial Gram slabs ----------------
__global__ __launch_bounds__(256) void gram_gemm(
    const float* __restrict__ X, float* __restrict__ Dp, int* __restrict__ ticket)
{
    // zero the ticket for kernel 2 (kernel boundary orders/flushes this)
    if (blockIdx.x == 0 && blockIdx.y == 0 && blockIdx.z == 0 && threadIdx.x == 0)
        *ticket = 0;

    __shared__ float As[TS][TS + 4];   // +4 keeps float4 alignment (144B rows)
    __shared__ float Bs[TS][TS + 4];

    const int tid   = threadIdx.x;
    const int row0  = blockIdx.y * TS;
    const int col0  = blockIdx.x * TS;
    const int kbase = blockIdx.z * (EMBED / KSPLIT);

    const int lr = tid >> 3;
    const int lc = (tid & 7) << 2;
    const int ty = tid >> 4;
    const int tx = tid & 15;

    float acc00 = 0.f, acc01 = 0.f, acc10 = 0.f, acc11 = 0.f;

    for (int kc = kbase; kc < kbase + EMBED / KSPLIT; kc += TS) {
        *(float4*)&As[lr][lc] = *(const float4*)(X + (size_t)(row0 + lr) * EMBED + kc + lc);
        *(float4*)&Bs[lr][lc] = *(const float4*)(X + (size_t)(col0 + lr) * EMBED + kc + lc);
        __syncthreads();

#pragma unroll
        for (int kk = 0; kk < TS; kk += 4) {
            float4 a0 = *(float4*)&As[ty][kk];
            float4 a1 = *(float4*)&As[ty + 16][kk];
            float4 b0 = *(float4*)&Bs[tx][kk];
            float4 b1 = *(float4*)&Bs[tx + 16][kk];
            acc00 = fmaf(a0.x, b0.x, acc00); acc00 = fmaf(a0.y, b0.y, acc00);
            acc00 = fmaf(a0.z, b0.z, acc00); acc00 = fmaf(a0.w, b0.w, acc00);
            acc01 = fmaf(a0.x, b1.x, acc01); acc01 = fmaf(a0.y, b1.y, acc01);
            acc01 = fmaf(a0.z, b1.z, acc01); acc01 = fmaf(a0.w, b1.w, acc01);
            acc10 = fmaf(a1.x, b0.x, acc10); acc10 = fmaf(a1.y, b0.y, acc10);
            acc10 = fmaf(a1.z, b0.z, acc10); acc10 = fmaf(a1.w, b0.w, acc10);
            acc11 = fmaf(a1.x, b1.x, acc11); acc11 = fmaf(a1.y, b1.y, acc11);
            acc11 = fmaf(a1.z, b1.z, acc11); acc11 = fmaf(a1.w, b1.w, acc11);
        }
        __syncthreads();
    }

    float* O = Dp + (size_t)blockIdx.z * BATCH * BATCH
                  + (size_t)(row0 + ty) * BATCH + col0 + tx;
    O[0]  = acc00;
    O[16] = acc01;
    O += (size_t)16 * BATCH;
    O[0]  = acc10;
    O[16] = acc11;
}

// ---------------- Kernel 2: hinge + tail-block finalize ----------------
__global__ __launch_bounds__(BLOCK) void hinge_reduce(
    const float* __restrict__ Dp,
    const int* __restrict__ labels,
    const float* __restrict__ mu,
    const float* __restrict__ nv,
    float* __restrict__ out,
    float* __restrict__ partial,
    int* __restrict__ ticket,
    int n_classes)
{
    __shared__ float drow[BATCH];
    __shared__ int   lab[BATCH];
    __shared__ int   poslist[BATCH];
    __shared__ float dijmu[BATCH];
    __shared__ int   npos_s;
    __shared__ float red[BLOCK / 64];
    __shared__ bool  is_last;

    const int i = blockIdx.x;
    const int tid = threadIdx.x;
    const int wave = tid >> 6;
    const int lane = tid & 63;

    if (tid == 0) npos_s = 0;
    for (int t = tid; t < BATCH; t += BLOCK) lab[t] = labels[t];
    if (tid < BATCH / 4) {
        float4 d0 = ((const float4*)(Dp + (size_t)i * BATCH))[tid];
        float4 d1 = ((const float4*)(Dp + (size_t)BATCH * BATCH + (size_t)i * BATCH))[tid];
        float4 s; s.x = d0.x + d1.x; s.y = d0.y + d1.y; s.z = d0.z + d1.z; s.w = d0.w + d1.w;
        ((float4*)drow)[tid] = s;
    }
    __syncthreads();

    const int li = lab[i];
    const float mu_i = mu[li];

    // compact positives j (same label, j != i)
    for (int t = tid; t < BATCH; t += BLOCK) {
        if (t != i && lab[t] == li) {
            int idx = atomicAdd(&npos_s, 1);
            poslist[idx] = t;
        }
    }
    __syncthreads();
    const int npos = npos_s;
    for (int t = tid; t < npos; t += BLOCK)
        dijmu[t] = drow[poslist[t]] + mu_i;
    __syncthreads();

    float local = 0.0f;
#pragma unroll
    for (int kk = 0; kk < BATCH / BLOCK; ++kk) {
        int k = tid + kk * BLOCK;
        if (lab[k] != li) {                 // k is a valid negative
            float dk = drow[k];
            for (int p = 0; p < npos; ++p)
                local += fmaxf(dijmu[p] - dk, 0.0f);
        }
    }

    // block reduce -> partial[i], then ticket
    for (int off = 32; off > 0; off >>= 1)
        local += __shfl_down(local, off, 64);
    if (lane == 0) red[wave] = local;
    __syncthreads();
    if (tid == 0) {
        float s = 0.f;
        for (int w = 0; w < BLOCK / 64; ++w) s += red[w];
        partial[i] = s;
        __threadfence();                    // release partial[i]
        int old = atomicAdd(ticket, 1);     // device-scope
        is_last = (old == (int)gridDim.x - 1);
    }
    __syncthreads();

    if (is_last) {
        __threadfence();                    // acquire all partials
        float loc = partial[tid] + partial[tid + BLOCK];
        if (tid < n_classes)
            loc -= (mu[tid] + nv[tid]) / (float)n_classes;
        for (int off = 32; off > 0; off >>= 1)
            loc += __shfl_down(loc, off, 64);
        if (lane == 0) red[wave] = loc;
        __syncthreads();
        if (tid == 0) {
            float s = 0.f;
            for (int w = 0; w < BLOCK / 64; ++w) s += red[w];
            *out = s;                       // plain store; no memset needed
        }
    }
}

extern "C" void kernel_launch(void* const* d_in, const int* in_sizes, int n_in,
                              void* d_out, int out_size, void* d_ws, size_t ws_size,
                              hipStream_t stream) {
    const float* X      = (const float*)d_in[0];
    const int*   labels = (const int*)d_in[1];
    const float* mu     = (const float*)d_in[2];
    const float* nv     = (const float*)d_in[3];
    float* out = (float*)d_out;
    float* Dp  = (float*)d_ws;                         // 2 slabs * 1 MB
    float* partial = Dp + (size_t)KSPLIT * BATCH * BATCH;
    int*   ticket  = (int*)(partial + BATCH);
    const int n_classes = in_sizes[2];

    dim3 ggrid(BATCH / TS, BATCH / TS, KSPLIT);        // 16x16x2 = 512 blocks
    gram_gemm<<<ggrid, dim3(256), 0, stream>>>(X, Dp, ticket);

    hinge_reduce<<<dim3(BATCH), dim3(BLOCK), 0, stream>>>(
        Dp, labels, mu, nv, out, partial, ticket, n_classes);
}

// Round 5
// 78.553 us; speedup vs baseline: 1.0603x; 1.0603x over previous
//
#include <hip/hip_runtime.h>

#define BATCH 512
#define EMBED 512
#define BLOCK 256
#define TS 32        // gram tile size
#define KSPLIT 2     // split-K slabs

// d_ws layout (floats): [0 .. 2*B*B) Dp partial gram slabs (2 MB)

// ---------------- Kernel 1: partial Gram slabs; also zeroes out ----------------
__global__ __launch_bounds__(256) void gram_gemm(
    const float* __restrict__ X, float* __restrict__ Dp, float* __restrict__ out)
{
    // zero the output accumulator for kernel 2 (kernel boundary orders this)
    if (blockIdx.x == 0 && blockIdx.y == 0 && blockIdx.z == 0 && threadIdx.x == 0)
        *out = 0.0f;

    __shared__ float As[TS][TS + 4];   // +4 keeps float4 alignment (144B rows)
    __shared__ float Bs[TS][TS + 4];

    const int tid   = threadIdx.x;
    const int row0  = blockIdx.y * TS;
    const int col0  = blockIdx.x * TS;
    const int kbase = blockIdx.z * (EMBED / KSPLIT);

    const int lr = tid >> 3;
    const int lc = (tid & 7) << 2;
    const int ty = tid >> 4;
    const int tx = tid & 15;

    float acc00 = 0.f, acc01 = 0.f, acc10 = 0.f, acc11 = 0.f;

    for (int kc = kbase; kc < kbase + EMBED / KSPLIT; kc += TS) {
        *(float4*)&As[lr][lc] = *(const float4*)(X + (size_t)(row0 + lr) * EMBED + kc + lc);
        *(float4*)&Bs[lr][lc] = *(const float4*)(X + (size_t)(col0 + lr) * EMBED + kc + lc);
        __syncthreads();

#pragma unroll
        for (int kk = 0; kk < TS; kk += 4) {
            float4 a0 = *(float4*)&As[ty][kk];
            float4 a1 = *(float4*)&As[ty + 16][kk];
            float4 b0 = *(float4*)&Bs[tx][kk];
            float4 b1 = *(float4*)&Bs[tx + 16][kk];
            acc00 = fmaf(a0.x, b0.x, acc00); acc00 = fmaf(a0.y, b0.y, acc00);
            acc00 = fmaf(a0.z, b0.z, acc00); acc00 = fmaf(a0.w, b0.w, acc00);
            acc01 = fmaf(a0.x, b1.x, acc01); acc01 = fmaf(a0.y, b1.y, acc01);
            acc01 = fmaf(a0.z, b1.z, acc01); acc01 = fmaf(a0.w, b1.w, acc01);
            acc10 = fmaf(a1.x, b0.x, acc10); acc10 = fmaf(a1.y, b0.y, acc10);
            acc10 = fmaf(a1.z, b0.z, acc10); acc10 = fmaf(a1.w, b0.w, acc10);
            acc11 = fmaf(a1.x, b1.x, acc11); acc11 = fmaf(a1.y, b1.y, acc11);
            acc11 = fmaf(a1.z, b1.z, acc11); acc11 = fmaf(a1.w, b1.w, acc11);
        }
        __syncthreads();
    }

    float* O = Dp + (size_t)blockIdx.z * BATCH * BATCH
                  + (size_t)(row0 + ty) * BATCH + col0 + tx;
    O[0]  = acc00;
    O[16] = acc01;
    O += (size_t)16 * BATCH;
    O[0]  = acc10;
    O[16] = acc11;
}

// ---------------- Kernel 2: hinge reduction, atomicAdd finalize ----------------
__global__ __launch_bounds__(BLOCK) void hinge_reduce(
    const float* __restrict__ Dp,
    const int* __restrict__ labels,
    const float* __restrict__ mu,
    const float* __restrict__ nv,
    float* __restrict__ out,
    int n_classes)
{
    __shared__ float drow[BATCH];
    __shared__ int   lab[BATCH];
    __shared__ int   poslist[BATCH];
    __shared__ float dijmu[BATCH];
    __shared__ int   npos_s;
    __shared__ float red[BLOCK / 64];

    const int i = blockIdx.x;
    const int tid = threadIdx.x;
    const int wave = tid >> 6;
    const int lane = tid & 63;

    if (tid == 0) npos_s = 0;
    for (int t = tid; t < BATCH; t += BLOCK) lab[t] = labels[t];
    if (tid < BATCH / 4) {
        float4 d0 = ((const float4*)(Dp + (size_t)i * BATCH))[tid];
        float4 d1 = ((const float4*)(Dp + (size_t)BATCH * BATCH + (size_t)i * BATCH))[tid];
        float4 s; s.x = d0.x + d1.x; s.y = d0.y + d1.y; s.z = d0.z + d1.z; s.w = d0.w + d1.w;
        ((float4*)drow)[tid] = s;
    }
    __syncthreads();

    const int li = lab[i];
    const float mu_i = mu[li];

    // compact positives j (same label, j != i)
    for (int t = tid; t < BATCH; t += BLOCK) {
        if (t != i && lab[t] == li) {
            int idx = atomicAdd(&npos_s, 1);
            poslist[idx] = t;
        }
    }
    __syncthreads();
    const int npos = npos_s;
    for (int t = tid; t < npos; t += BLOCK)
        dijmu[t] = drow[poslist[t]] + mu_i;
    __syncthreads();

    float local = 0.0f;
#pragma unroll
    for (int kk = 0; kk < BATCH / BLOCK; ++kk) {
        int k = tid + kk * BLOCK;
        if (lab[k] != li) {                 // k is a valid negative
            float dk = drow[k];
            for (int p = 0; p < npos; ++p)
                local += fmaxf(dijmu[p] - dk, 0.0f);
        }
    }

    // regularizer folded by block 0
    if (i == 0 && tid < n_classes)
        local -= (mu[tid] + nv[tid]) / (float)n_classes;

    for (int off = 32; off > 0; off >>= 1)
        local += __shfl_down(local, off, 64);
    if (lane == 0) red[wave] = local;
    __syncthreads();
    if (tid == 0) {
        float s = 0.f;
        for (int w = 0; w < BLOCK / 64; ++w) s += red[w];
        atomicAdd(out, s);                  // device-scope; out zeroed by gram_gemm
    }
}

extern "C" void kernel_launch(void* const* d_in, const int* in_sizes, int n_in,
                              void* d_out, int out_size, void* d_ws, size_t ws_size,
                              hipStream_t stream) {
    const float* X      = (const float*)d_in[0];
    const int*   labels = (const int*)d_in[1];
    const float* mu     = (const float*)d_in[2];
    const float* nv     = (const float*)d_in[3];
    float* out = (float*)d_out;
    float* Dp  = (float*)d_ws;                         // 2 slabs * 1 MB
    const int n_classes = in_sizes[2];

    dim3 ggrid(BATCH / TS, BATCH / TS, KSPLIT);        // 16x16x2 = 512 blocks
    gram_gemm<<<ggrid, dim3(256), 0, stream>>>(X, Dp, out);

    hinge_reduce<<<dim3(BATCH), dim3(BLOCK), 0, stream>>>(
        Dp, labels, mu, nv, out, n_classes);
}